// Round 9
// baseline (693.505 us; speedup 1.0000x reference)
//
#include <hip/hip_runtime.h>
#include <hip/hip_cooperative_groups.h>
#include <math.h>
#include <stdint.h>

// Problem constants (match reference)
#define BB 65536
#define KK 10
#define EE 128
#define VV 100000

constexpr int BLOCK = 256;
constexpr int BPB   = 32;            // 32 groups of 8 lanes per block
constexpr int GRID  = BB / BPB;      // 2048 blocks (fp8 path)

constexpr size_t TBL_OFF   = 32768;              // fp8 table offset in ws
constexpr size_t TBL_BYTES = (size_t)VV * EE;    // 12.8 MB fp8

__device__ __forceinline__ float softplus_f(float x) {
    float ax = fabsf(x);
    return fmaxf(x, 0.0f) + __logf(1.0f + __expf(-ax));
}

// ---- shared device helpers ----------------------------------------------
__device__ __forceinline__ void convert16(const float4* src, uint4* dst) {
    const float4 f0 = src[0], f1 = src[1], f2 = src[2], f3 = src[3];
    uint32_t w[4];
    int v;
    v = 0;
    v = __builtin_amdgcn_cvt_pk_fp8_f32(f0.x, f0.y, v, false);
    v = __builtin_amdgcn_cvt_pk_fp8_f32(f0.z, f0.w, v, true);
    w[0] = (uint32_t)v;
    v = 0;
    v = __builtin_amdgcn_cvt_pk_fp8_f32(f1.x, f1.y, v, false);
    v = __builtin_amdgcn_cvt_pk_fp8_f32(f1.z, f1.w, v, true);
    w[1] = (uint32_t)v;
    v = 0;
    v = __builtin_amdgcn_cvt_pk_fp8_f32(f2.x, f2.y, v, false);
    v = __builtin_amdgcn_cvt_pk_fp8_f32(f2.z, f2.w, v, true);
    w[2] = (uint32_t)v;
    v = 0;
    v = __builtin_amdgcn_cvt_pk_fp8_f32(f3.x, f3.y, v, false);
    v = __builtin_amdgcn_cvt_pk_fp8_f32(f3.z, f3.w, v, true);
    w[3] = (uint32_t)v;
    *dst = make_uint4(w[0], w[1], w[2], w[3]);
}

__device__ __forceinline__ void decode16(const uint4& u, float* f) {
    const uint32_t a[4] = {u.x, u.y, u.z, u.w};
    #pragma unroll
    for (int i = 0; i < 4; ++i) {
        auto lo = __builtin_amdgcn_cvt_pk_f32_fp8((int)a[i], false);
        auto hi = __builtin_amdgcn_cvt_pk_f32_fp8((int)a[i], true);
        f[4 * i + 0] = lo[0];
        f[4 * i + 1] = lo[1];
        f[4 * i + 2] = hi[0];
        f[4 * i + 3] = hi[1];
    }
}

__device__ __forceinline__ float dotd16(const float* cf, const uint4& u) {
    const uint32_t a[4] = {u.x, u.y, u.z, u.w};
    float s = 0.0f;
    #pragma unroll
    for (int i = 0; i < 4; ++i) {
        auto lo = __builtin_amdgcn_cvt_pk_f32_fp8((int)a[i], false);
        auto hi = __builtin_amdgcn_cvt_pk_f32_fp8((int)a[i], true);
        s = fmaf(cf[4 * i + 0], lo[0], s);
        s = fmaf(cf[4 * i + 1], lo[1], s);
        s = fmaf(cf[4 * i + 2], hi[0], s);
        s = fmaf(cf[4 * i + 3], hi[1], s);
    }
    return s;
}

// ---- fused cooperative kernel: convert | sync | loss | sync | reduce -----
__global__ __launch_bounds__(BLOCK, 8) void
w2v_fused_kernel(const int* __restrict__ cw,
                 const int* __restrict__ ow,
                 const int* __restrict__ neg,
                 const float* __restrict__ emb,
                 uint4* __restrict__ tbl,
                 float* __restrict__ partial,
                 float* __restrict__ out) {
    const int tid = threadIdx.x;

    // ---- Phase 1: fp32 -> fp8 e4m3 table conversion (grid-stride) ----
    {
        const int nq = VV * EE / 16;
        const int stride = gridDim.x * blockDim.x;
        for (int q = blockIdx.x * blockDim.x + tid; q < nq; q += stride)
            convert16((const float4*)emb + (size_t)q * 4, tbl + q);
    }
    __threadfence();
    cooperative_groups::this_grid().sync();

    // ---- Phase 2: gather + loss (round-4 body) ----
    const int li  = tid & 7;
    const int grp = tid >> 3;
    __shared__ float smem[BPB];
    float acc = 0.0f;
    const uint4* rows = (const uint4*)tbl;
    for (int chunk = blockIdx.x; chunk < BB / BPB; chunk += gridDim.x) {
        const int b = chunk * BPB + grp;
        const int c = cw[b];
        const int o = ow[b];

        const uint4 ec = rows[(size_t)c * 8 + li];
        float cf[16];
        decode16(ec, cf);

        const uint4 eo = rows[(size_t)o * 8 + li];
        float pd = dotd16(cf, eo);

        float nd[KK];
        #pragma unroll
        for (int k = 0; k < KK; ++k) {
            const int n = neg[b * KK + k];
            const uint4 en = rows[(size_t)n * 8 + li];
            nd[k] = dotd16(cf, en);
        }

        #pragma unroll
        for (int s = 1; s < 8; s <<= 1) {
            pd += __shfl_xor(pd, s);
            #pragma unroll
            for (int k = 0; k < KK; ++k) nd[k] += __shfl_xor(nd[k], s);
        }

        float loss = softplus_f(-pd);
        #pragma unroll
        for (int k = 0; k < KK; ++k) loss += softplus_f(nd[k]);

        if (li == 0) smem[grp] = loss;
        __syncthreads();
        if (tid == 0) {
            float s = 0.0f;
            #pragma unroll
            for (int g = 0; g < BPB; ++g) s += smem[g];
            acc += s;
        }
        __syncthreads();
    }
    if (tid == 0) partial[blockIdx.x] = acc;
    __threadfence();
    cooperative_groups::this_grid().sync();

    // ---- Phase 3: block 0 reduces all partials ----
    if (blockIdx.x == 0) {
        __shared__ float r[256];
        float s = 0.0f;
        for (int i = tid; i < (int)gridDim.x; i += 256) s += partial[i];
        r[tid] = s;
        __syncthreads();
        for (int step = 128; step > 0; step >>= 1) {
            if (tid < step) r[tid] += r[tid + step];
            __syncthreads();
        }
        if (tid == 0) out[0] = r[0] / (float)BB;
    }
}

// ---- standalone kernels (fallback path, proven round-4 code) -------------
__global__ __launch_bounds__(256) void
convert_fp8_kernel(const float* __restrict__ emb, uint4* __restrict__ tbl) {
    const int nq = VV * EE / 16;
    const int stride = gridDim.x * blockDim.x;
    for (int q = blockIdx.x * blockDim.x + threadIdx.x; q < nq; q += stride)
        convert16((const float4*)emb + (size_t)q * 4, tbl + q);
}

__global__ __launch_bounds__(BLOCK) void
w2v_loss_fp8_kernel(const int* __restrict__ cw,
                    const int* __restrict__ ow,
                    const int* __restrict__ neg,
                    const uint4* __restrict__ rows,
                    float* __restrict__ partial) {
    const int tid = threadIdx.x;
    const int li  = tid & 7;
    const int grp = tid >> 3;
    const int b   = blockIdx.x * BPB + grp;

    const int c = cw[b];
    const int o = ow[b];

    const uint4 ec = rows[(size_t)c * 8 + li];
    float cf[16];
    decode16(ec, cf);

    const uint4 eo = rows[(size_t)o * 8 + li];
    float pd = dotd16(cf, eo);

    float nd[KK];
    #pragma unroll
    for (int k = 0; k < KK; ++k) {
        const int n = neg[b * KK + k];
        const uint4 en = rows[(size_t)n * 8 + li];
        nd[k] = dotd16(cf, en);
    }

    #pragma unroll
    for (int s = 1; s < 8; s <<= 1) {
        pd += __shfl_xor(pd, s);
        #pragma unroll
        for (int k = 0; k < KK; ++k) nd[k] += __shfl_xor(nd[k], s);
    }

    float loss = softplus_f(-pd);
    #pragma unroll
    for (int k = 0; k < KK; ++k) loss += softplus_f(nd[k]);

    __shared__ float smem[BPB];
    if (li == 0) smem[grp] = loss;
    __syncthreads();
    if (tid == 0) {
        float s = 0.0f;
        #pragma unroll
        for (int g = 0; g < BPB; ++g) s += smem[g];
        partial[blockIdx.x] = s;
    }
}

__global__ __launch_bounds__(256) void
w2v_reduce_kernel(const float* __restrict__ partial, int n, float* __restrict__ out) {
    __shared__ float smem[256];
    float s = 0.0f;
    for (int i = threadIdx.x; i < n; i += 256) s += partial[i];
    smem[threadIdx.x] = s;
    __syncthreads();
    for (int step = 128; step > 0; step >>= 1) {
        if (threadIdx.x < step) smem[threadIdx.x] += smem[threadIdx.x + step];
        __syncthreads();
    }
    if (threadIdx.x == 0) out[0] = smem[0] / (float)BB;
}

// ---- fp32 fallback (ws too small) ---------------------------------------
__device__ __forceinline__ float dot8(const float4& a0, const float4& a1,
                                      const float4& b0, const float4& b1) {
    float s = a0.x * b0.x;
    s = fmaf(a0.y, b0.y, s); s = fmaf(a0.z, b0.z, s); s = fmaf(a0.w, b0.w, s);
    s = fmaf(a1.x, b1.x, s); s = fmaf(a1.y, b1.y, s);
    s = fmaf(a1.z, b1.z, s); s = fmaf(a1.w, b1.w, s);
    return s;
}

__global__ __launch_bounds__(BLOCK) void
w2v_loss_f32_kernel(const int* __restrict__ cw,
                    const int* __restrict__ ow,
                    const int* __restrict__ neg,
                    const float* __restrict__ emb,
                    float* __restrict__ partial) {
    const int tid = threadIdx.x;
    const int li  = tid & 15;
    const int grp = tid >> 4;
    const int b   = blockIdx.x * 16 + grp;

    const int c = cw[b];
    const int o = ow[b];
    const float4* ebase = (const float4*)emb;
    const size_t f4 = (size_t)li * 2;

    const float4 ec0 = ebase[(size_t)c * 32 + f4];
    const float4 ec1 = ebase[(size_t)c * 32 + f4 + 1];
    const float4 eo0 = ebase[(size_t)o * 32 + f4];
    const float4 eo1 = ebase[(size_t)o * 32 + f4 + 1];

    float pd = dot8(ec0, ec1, eo0, eo1);
    float nd[KK];
    #pragma unroll
    for (int k = 0; k < KK; ++k) {
        const int n = neg[b * KK + k];
        const float4 en0 = ebase[(size_t)n * 32 + f4];
        const float4 en1 = ebase[(size_t)n * 32 + f4 + 1];
        nd[k] = dot8(ec0, ec1, en0, en1);
    }
    #pragma unroll
    for (int s = 1; s < 16; s <<= 1) {
        pd += __shfl_xor(pd, s);
        #pragma unroll
        for (int k = 0; k < KK; ++k) nd[k] += __shfl_xor(nd[k], s);
    }
    float loss = softplus_f(-pd);
    #pragma unroll
    for (int k = 0; k < KK; ++k) loss += softplus_f(nd[k]);

    __shared__ float smem[16];
    if (li == 0) smem[grp] = loss;
    __syncthreads();
    if (tid == 0) {
        float s = 0.0f;
        #pragma unroll
        for (int g = 0; g < 16; ++g) s += smem[g];
        partial[blockIdx.x] = s;
    }
}

extern "C" void kernel_launch(void* const* d_in, const int* in_sizes, int n_in,
                              void* d_out, int out_size, void* d_ws, size_t ws_size,
                              hipStream_t stream) {
    const int*   cw  = (const int*)d_in[0];
    const int*   ow  = (const int*)d_in[1];
    const int*   neg = (const int*)d_in[2];
    const float* emb = (const float*)d_in[3];
    float* out     = (float*)d_out;
    float* partial = (float*)d_ws;

    if (ws_size >= TBL_OFF + TBL_BYTES) {
        uint4* tbl = (uint4*)((char*)d_ws + TBL_OFF);
        void* args[] = {(void*)&cw, (void*)&ow, (void*)&neg, (void*)&emb,
                        (void*)&tbl, (void*)&partial, (void*)&out};
        hipError_t e = hipLaunchCooperativeKernel((void*)w2v_fused_kernel,
                                                  dim3(GRID), dim3(BLOCK),
                                                  args, 0, stream);
        if (e != hipSuccess) {
            (void)hipGetLastError();   // clear; fall back to 3-kernel path
            convert_fp8_kernel<<<2048, 256, 0, stream>>>(emb, tbl);
            w2v_loss_fp8_kernel<<<GRID, BLOCK, 0, stream>>>(cw, ow, neg, tbl, partial);
            w2v_reduce_kernel<<<1, 256, 0, stream>>>(partial, GRID, out);
        }
    } else {
        w2v_loss_f32_kernel<<<BB / 16, BLOCK, 0, stream>>>(cw, ow, neg, emb, partial);
        w2v_reduce_kernel<<<1, 256, 0, stream>>>(partial, BB / 16, out);
    }
}

// Round 10
// 86.004 us; speedup vs baseline: 8.0636x; 8.0636x over previous
//
#include <hip/hip_runtime.h>
#include <math.h>
#include <stdint.h>

// Problem constants (match reference)
#define BB 65536
#define KK 10
#define EE 128
#define VV 100000

constexpr int BLOCK = 256;
constexpr int BPB   = 32;            // 32 groups of 8 lanes per block
constexpr int GRID  = BB / BPB;      // 2048 blocks (fp8 path)

// ws layout:
//   [0,      8K)   partial[2048] floats            (fp8 path)
//   [0,     16K)   partial[4096] floats            (fp32 fallback path)
//   [16K,   24K)   cnt1[64] uints, 128B apart      (fp8 path)
//   [24K,  24K+4)  cnt2 uint                       (fp8 path)
//   [32K,  ...)    fp8 table (12.8 MB)
constexpr size_t CNT1_OFF  = 16384;
constexpr size_t CNT2_OFF  = 24576;
constexpr size_t TBL_OFF   = 32768;
constexpr size_t TBL_BYTES = (size_t)VV * EE;    // 12.8 MB fp8

__device__ __forceinline__ float softplus_f(float x) {
    float ax = fabsf(x);
    return fmaxf(x, 0.0f) + __logf(1.0f + __expf(-ax));
}

// ---- shared device helpers ----------------------------------------------
__device__ __forceinline__ void convert16(const float4* src, uint4* dst) {
    const float4 f0 = src[0], f1 = src[1], f2 = src[2], f3 = src[3];
    uint32_t w[4];
    int v;
    v = 0;
    v = __builtin_amdgcn_cvt_pk_fp8_f32(f0.x, f0.y, v, false);
    v = __builtin_amdgcn_cvt_pk_fp8_f32(f0.z, f0.w, v, true);
    w[0] = (uint32_t)v;
    v = 0;
    v = __builtin_amdgcn_cvt_pk_fp8_f32(f1.x, f1.y, v, false);
    v = __builtin_amdgcn_cvt_pk_fp8_f32(f1.z, f1.w, v, true);
    w[1] = (uint32_t)v;
    v = 0;
    v = __builtin_amdgcn_cvt_pk_fp8_f32(f2.x, f2.y, v, false);
    v = __builtin_amdgcn_cvt_pk_fp8_f32(f2.z, f2.w, v, true);
    w[2] = (uint32_t)v;
    v = 0;
    v = __builtin_amdgcn_cvt_pk_fp8_f32(f3.x, f3.y, v, false);
    v = __builtin_amdgcn_cvt_pk_fp8_f32(f3.z, f3.w, v, true);
    w[3] = (uint32_t)v;
    *dst = make_uint4(w[0], w[1], w[2], w[3]);
}

__device__ __forceinline__ void decode16(const uint4& u, float* f) {
    const uint32_t a[4] = {u.x, u.y, u.z, u.w};
    #pragma unroll
    for (int i = 0; i < 4; ++i) {
        auto lo = __builtin_amdgcn_cvt_pk_f32_fp8((int)a[i], false);
        auto hi = __builtin_amdgcn_cvt_pk_f32_fp8((int)a[i], true);
        f[4 * i + 0] = lo[0];
        f[4 * i + 1] = lo[1];
        f[4 * i + 2] = hi[0];
        f[4 * i + 3] = hi[1];
    }
}

__device__ __forceinline__ float dotd16(const float* cf, const uint4& u) {
    const uint32_t a[4] = {u.x, u.y, u.z, u.w};
    float s = 0.0f;
    #pragma unroll
    for (int i = 0; i < 4; ++i) {
        auto lo = __builtin_amdgcn_cvt_pk_f32_fp8((int)a[i], false);
        auto hi = __builtin_amdgcn_cvt_pk_f32_fp8((int)a[i], true);
        s = fmaf(cf[4 * i + 0], lo[0], s);
        s = fmaf(cf[4 * i + 1], lo[1], s);
        s = fmaf(cf[4 * i + 2], hi[0], s);
        s = fmaf(cf[4 * i + 3], hi[1], s);
    }
    return s;
}

// ---- kernel 1: fp32 -> fp8 e4m3 table conversion + counter zeroing -------
__global__ __launch_bounds__(256) void
convert_fp8_kernel(const float* __restrict__ emb, uint4* __restrict__ tbl,
                   unsigned int* __restrict__ cnt1,   // 64 slots, 32-uint stride
                   unsigned int* __restrict__ cnt2) {
    if (blockIdx.x == 0) {
        if (threadIdx.x < 64) cnt1[threadIdx.x * 32] = 0u;
        else if (threadIdx.x == 64) cnt2[0] = 0u;
    }
    const int nq = VV * EE / 16;
    const int stride = gridDim.x * blockDim.x;
    for (int q = blockIdx.x * blockDim.x + threadIdx.x; q < nq; q += stride)
        convert16((const float4*)emb + (size_t)q * 4, tbl + q);
}

// ---- kernel 2: gather + loss + hierarchical last-block reduce ------------
__global__ __launch_bounds__(BLOCK) void
w2v_loss_fp8_kernel(const int* __restrict__ cw,
                    const int* __restrict__ ow,
                    const int* __restrict__ neg,
                    const uint4* __restrict__ rows,   // one row = 8 uint4 (128 B)
                    float* __restrict__ partial,
                    unsigned int* __restrict__ cnt1,
                    unsigned int* __restrict__ cnt2,
                    float* __restrict__ out) {
    const int tid = threadIdx.x;
    const int li  = tid & 7;               // lane-in-group (8-lane groups)
    const int grp = tid >> 3;              // 0..31
    const int b   = blockIdx.x * BPB + grp;

    const int c = cw[b];
    const int o = ow[b];

    const uint4 ec = rows[(size_t)c * 8 + li];
    float cf[16];
    decode16(ec, cf);

    const uint4 eo = rows[(size_t)o * 8 + li];
    float pd = dotd16(cf, eo);

    float nd[KK];
    #pragma unroll
    for (int k = 0; k < KK; ++k) {
        const int n = neg[b * KK + k];
        const uint4 en = rows[(size_t)n * 8 + li];
        nd[k] = dotd16(cf, en);
    }

    // Reduce across the 8-lane group: masks 1,2,4.
    #pragma unroll
    for (int s = 1; s < 8; s <<= 1) {
        pd += __shfl_xor(pd, s);
        #pragma unroll
        for (int k = 0; k < KK; ++k) nd[k] += __shfl_xor(nd[k], s);
    }

    float loss = softplus_f(-pd);
    #pragma unroll
    for (int k = 0; k < KK; ++k) loss += softplus_f(nd[k]);

    __shared__ float smem[BPB];
    __shared__ unsigned int s_last;
    if (li == 0) smem[grp] = loss;
    __syncthreads();
    if (tid == 0) {
        float s = 0.0f;
        #pragma unroll
        for (int g = 0; g < BPB; ++g) s += smem[g];
        partial[blockIdx.x] = s;
        __threadfence();                           // release partial
        unsigned int last = 0u;
        const unsigned int slot = blockIdx.x & 63u;
        // Round-robin dispatch puts all 32 blocks of a slot on one XCD:
        // cnt1[slot] stays in its home L2 -> cheap local atomics.
        if (atomicAdd(&cnt1[slot * 32], 1u) == 31u) {
            if (atomicAdd(cnt2, 1u) == 63u) last = 1u;   // last block overall
        }
        s_last = last;
    }
    __syncthreads();

    if (s_last) {
        __threadfence();                           // acquire all partials
        __shared__ float red[BLOCK];
        float s = 0.0f;
        for (int i = tid; i < GRID; i += BLOCK) s += partial[i];
        red[tid] = s;
        __syncthreads();
        #pragma unroll
        for (int step = BLOCK / 2; step > 0; step >>= 1) {
            if (tid < step) red[tid] += red[tid + step];
            __syncthreads();
        }
        if (tid == 0) out[0] = red[0] / (float)BB;
    }
}

// ---- fp32 fallback (ws too small; round-2 structure) --------------------
__device__ __forceinline__ float dot8(const float4& a0, const float4& a1,
                                      const float4& b0, const float4& b1) {
    float s = a0.x * b0.x;
    s = fmaf(a0.y, b0.y, s); s = fmaf(a0.z, b0.z, s); s = fmaf(a0.w, b0.w, s);
    s = fmaf(a1.x, b1.x, s); s = fmaf(a1.y, b1.y, s);
    s = fmaf(a1.z, b1.z, s); s = fmaf(a1.w, b1.w, s);
    return s;
}

__global__ __launch_bounds__(BLOCK) void
w2v_loss_f32_kernel(const int* __restrict__ cw,
                    const int* __restrict__ ow,
                    const int* __restrict__ neg,
                    const float* __restrict__ emb,
                    float* __restrict__ partial) {
    const int tid = threadIdx.x;
    const int li  = tid & 15;
    const int grp = tid >> 4;
    const int b   = blockIdx.x * 16 + grp;

    const int c = cw[b];
    const int o = ow[b];
    const float4* ebase = (const float4*)emb;
    const size_t f4 = (size_t)li * 2;

    const float4 ec0 = ebase[(size_t)c * 32 + f4];
    const float4 ec1 = ebase[(size_t)c * 32 + f4 + 1];
    const float4 eo0 = ebase[(size_t)o * 32 + f4];
    const float4 eo1 = ebase[(size_t)o * 32 + f4 + 1];

    float pd = dot8(ec0, ec1, eo0, eo1);
    float nd[KK];
    #pragma unroll
    for (int k = 0; k < KK; ++k) {
        const int n = neg[b * KK + k];
        const float4 en0 = ebase[(size_t)n * 32 + f4];
        const float4 en1 = ebase[(size_t)n * 32 + f4 + 1];
        nd[k] = dot8(ec0, ec1, en0, en1);
    }
    #pragma unroll
    for (int s = 1; s < 16; s <<= 1) {
        pd += __shfl_xor(pd, s);
        #pragma unroll
        for (int k = 0; k < KK; ++k) nd[k] += __shfl_xor(nd[k], s);
    }
    float loss = softplus_f(-pd);
    #pragma unroll
    for (int k = 0; k < KK; ++k) loss += softplus_f(nd[k]);

    __shared__ float smem[16];
    if (li == 0) smem[grp] = loss;
    __syncthreads();
    if (tid == 0) {
        float s = 0.0f;
        #pragma unroll
        for (int g = 0; g < 16; ++g) s += smem[g];
        partial[blockIdx.x] = s;
    }
}

__global__ __launch_bounds__(256) void
w2v_reduce_kernel(const float* __restrict__ partial, int n, float* __restrict__ out) {
    __shared__ float smem[256];
    float s = 0.0f;
    for (int i = threadIdx.x; i < n; i += 256) s += partial[i];
    smem[threadIdx.x] = s;
    __syncthreads();
    for (int step = 128; step > 0; step >>= 1) {
        if (threadIdx.x < step) smem[threadIdx.x] += smem[threadIdx.x + step];
        __syncthreads();
    }
    if (threadIdx.x == 0) out[0] = smem[0] / (float)BB;
}

extern "C" void kernel_launch(void* const* d_in, const int* in_sizes, int n_in,
                              void* d_out, int out_size, void* d_ws, size_t ws_size,
                              hipStream_t stream) {
    const int*   cw  = (const int*)d_in[0];
    const int*   ow  = (const int*)d_in[1];
    const int*   neg = (const int*)d_in[2];
    const float* emb = (const float*)d_in[3];
    float* out     = (float*)d_out;
    float* partial = (float*)d_ws;

    if (ws_size >= TBL_OFF + TBL_BYTES) {
        uint4*        tbl  = (uint4*)((char*)d_ws + TBL_OFF);
        unsigned int* cnt1 = (unsigned int*)((char*)d_ws + CNT1_OFF);
        unsigned int* cnt2 = (unsigned int*)((char*)d_ws + CNT2_OFF);
        convert_fp8_kernel<<<2048, 256, 0, stream>>>(emb, tbl, cnt1, cnt2);
        w2v_loss_fp8_kernel<<<GRID, BLOCK, 0, stream>>>(cw, ow, neg, tbl, partial,
                                                        cnt1, cnt2, out);
    } else {
        w2v_loss_f32_kernel<<<BB / 16, BLOCK, 0, stream>>>(cw, ow, neg, emb, partial);
        w2v_reduce_kernel<<<1, 256, 0, stream>>>(partial, BB / 16, out);
    }
}

// Round 11
// 33.707 us; speedup vs baseline: 20.5747x; 2.5516x over previous
//
#include <hip/hip_runtime.h>
#include <math.h>
#include <stdint.h>

// Problem constants (match reference)
#define BB 65536
#define KK 10
#define EE 128
#define VV 100000

constexpr int BLOCK = 256;
constexpr int BPB   = 32;            // 32 groups of 8 lanes per block
constexpr int GRID  = BB / BPB;      // 2048 blocks (fp8 path)

constexpr size_t TBL_OFF   = 32768;              // fp8 table offset in ws
constexpr size_t TBL_BYTES = (size_t)VV * EE;    // 12.8 MB fp8

__device__ __forceinline__ float softplus_f(float x) {
    float ax = fabsf(x);
    return fmaxf(x, 0.0f) + __logf(1.0f + __expf(-ax));
}

// ---- fp32 -> fp8 e4m3 (RNE, HW cvt) table conversion --------------------
__global__ __launch_bounds__(256) void
convert_fp8_kernel(const float* __restrict__ emb, uint4* __restrict__ tbl) {
    const int nq = VV * EE / 16;                 // 800K chunks of 16 elems
    const int q = blockIdx.x * blockDim.x + threadIdx.x;
    if (q >= nq) return;
    const float4* src = (const float4*)emb + (size_t)q * 4;
    const float4 f0 = src[0], f1 = src[1], f2 = src[2], f3 = src[3];
    uint32_t w[4];
    int v;
    v = 0;
    v = __builtin_amdgcn_cvt_pk_fp8_f32(f0.x, f0.y, v, false);
    v = __builtin_amdgcn_cvt_pk_fp8_f32(f0.z, f0.w, v, true);
    w[0] = (uint32_t)v;
    v = 0;
    v = __builtin_amdgcn_cvt_pk_fp8_f32(f1.x, f1.y, v, false);
    v = __builtin_amdgcn_cvt_pk_fp8_f32(f1.z, f1.w, v, true);
    w[1] = (uint32_t)v;
    v = 0;
    v = __builtin_amdgcn_cvt_pk_fp8_f32(f2.x, f2.y, v, false);
    v = __builtin_amdgcn_cvt_pk_fp8_f32(f2.z, f2.w, v, true);
    w[2] = (uint32_t)v;
    v = 0;
    v = __builtin_amdgcn_cvt_pk_fp8_f32(f3.x, f3.y, v, false);
    v = __builtin_amdgcn_cvt_pk_fp8_f32(f3.z, f3.w, v, true);
    w[3] = (uint32_t)v;
    tbl[q] = make_uint4(w[0], w[1], w[2], w[3]);
}

// ---- fp8 gather + loss (round-4 structure: k-loop loads, max TLP) --------
__device__ __forceinline__ void decode16(const uint4& u, float* f) {
    const uint32_t a[4] = {u.x, u.y, u.z, u.w};
    #pragma unroll
    for (int i = 0; i < 4; ++i) {
        auto lo = __builtin_amdgcn_cvt_pk_f32_fp8((int)a[i], false);
        auto hi = __builtin_amdgcn_cvt_pk_f32_fp8((int)a[i], true);
        f[4 * i + 0] = lo[0];
        f[4 * i + 1] = lo[1];
        f[4 * i + 2] = hi[0];
        f[4 * i + 3] = hi[1];
    }
}

__device__ __forceinline__ float dotd16(const float* cf, const uint4& u) {
    const uint32_t a[4] = {u.x, u.y, u.z, u.w};
    float s = 0.0f;
    #pragma unroll
    for (int i = 0; i < 4; ++i) {
        auto lo = __builtin_amdgcn_cvt_pk_f32_fp8((int)a[i], false);
        auto hi = __builtin_amdgcn_cvt_pk_f32_fp8((int)a[i], true);
        s = fmaf(cf[4 * i + 0], lo[0], s);
        s = fmaf(cf[4 * i + 1], lo[1], s);
        s = fmaf(cf[4 * i + 2], hi[0], s);
        s = fmaf(cf[4 * i + 3], hi[1], s);
    }
    return s;
}

__global__ __launch_bounds__(BLOCK) void
w2v_loss_fp8_kernel(const int* __restrict__ cw,
                    const int* __restrict__ ow,
                    const int* __restrict__ neg,
                    const uint4* __restrict__ rows,   // one row = 8 uint4 (128 B)
                    float* __restrict__ partial) {
    const int tid = threadIdx.x;
    const int li  = tid & 7;               // lane-in-group (8-lane groups)
    const int grp = tid >> 3;              // 0..31
    const int b   = blockIdx.x * BPB + grp;

    const int c = cw[b];
    const int o = ow[b];

    const uint4 ec = rows[(size_t)c * 8 + li];
    float cf[16];
    decode16(ec, cf);

    const uint4 eo = rows[(size_t)o * 8 + li];
    float pd = dotd16(cf, eo);

    float nd[KK];
    #pragma unroll
    for (int k = 0; k < KK; ++k) {
        const int n = neg[b * KK + k];
        const uint4 en = rows[(size_t)n * 8 + li];
        nd[k] = dotd16(cf, en);
    }

    // Reduce across the 8-lane group: masks 1,2,4.
    #pragma unroll
    for (int s = 1; s < 8; s <<= 1) {
        pd += __shfl_xor(pd, s);
        #pragma unroll
        for (int k = 0; k < KK; ++k) nd[k] += __shfl_xor(nd[k], s);
    }

    float loss = softplus_f(-pd);
    #pragma unroll
    for (int k = 0; k < KK; ++k) loss += softplus_f(nd[k]);

    __shared__ float smem[BPB];
    if (li == 0) smem[grp] = loss;
    __syncthreads();
    if (tid == 0) {
        float s = 0.0f;
        #pragma unroll
        for (int g = 0; g < BPB; ++g) s += smem[g];
        partial[blockIdx.x] = s;     // per-block partial; no cross-XCD atomics
    }
}

// ---- fp32 fallback (ws too small; round-2 structure) --------------------
__device__ __forceinline__ float dot8(const float4& a0, const float4& a1,
                                      const float4& b0, const float4& b1) {
    float s = a0.x * b0.x;
    s = fmaf(a0.y, b0.y, s); s = fmaf(a0.z, b0.z, s); s = fmaf(a0.w, b0.w, s);
    s = fmaf(a1.x, b1.x, s); s = fmaf(a1.y, b1.y, s);
    s = fmaf(a1.z, b1.z, s); s = fmaf(a1.w, b1.w, s);
    return s;
}

__global__ __launch_bounds__(BLOCK) void
w2v_loss_f32_kernel(const int* __restrict__ cw,
                    const int* __restrict__ ow,
                    const int* __restrict__ neg,
                    const float* __restrict__ emb,
                    float* __restrict__ partial) {
    const int tid = threadIdx.x;
    const int li  = tid & 15;
    const int grp = tid >> 4;
    const int b   = blockIdx.x * 16 + grp;

    const int c = cw[b];
    const int o = ow[b];
    const float4* ebase = (const float4*)emb;
    const size_t f4 = (size_t)li * 2;

    const float4 ec0 = ebase[(size_t)c * 32 + f4];
    const float4 ec1 = ebase[(size_t)c * 32 + f4 + 1];
    const float4 eo0 = ebase[(size_t)o * 32 + f4];
    const float4 eo1 = ebase[(size_t)o * 32 + f4 + 1];

    float pd = dot8(ec0, ec1, eo0, eo1);
    float nd[KK];
    #pragma unroll
    for (int k = 0; k < KK; ++k) {
        const int n = neg[b * KK + k];
        const float4 en0 = ebase[(size_t)n * 32 + f4];
        const float4 en1 = ebase[(size_t)n * 32 + f4 + 1];
        nd[k] = dot8(ec0, ec1, en0, en1);
    }
    #pragma unroll
    for (int s = 1; s < 16; s <<= 1) {
        pd += __shfl_xor(pd, s);
        #pragma unroll
        for (int k = 0; k < KK; ++k) nd[k] += __shfl_xor(nd[k], s);
    }
    float loss = softplus_f(-pd);
    #pragma unroll
    for (int k = 0; k < KK; ++k) loss += softplus_f(nd[k]);

    __shared__ float smem[16];
    if (li == 0) smem[grp] = loss;
    __syncthreads();
    if (tid == 0) {
        float s = 0.0f;
        #pragma unroll
        for (int g = 0; g < 16; ++g) s += smem[g];
        partial[blockIdx.x] = s;
    }
}

__global__ __launch_bounds__(256) void
w2v_reduce_kernel(const float* __restrict__ partial, int n, float* __restrict__ out) {
    __shared__ float smem[256];
    float s = 0.0f;
    for (int i = threadIdx.x; i < n; i += 256) s += partial[i];
    smem[threadIdx.x] = s;
    __syncthreads();
    for (int step = 128; step > 0; step >>= 1) {
        if (threadIdx.x < step) smem[threadIdx.x] += smem[threadIdx.x + step];
        __syncthreads();
    }
    if (threadIdx.x == 0) out[0] = smem[0] / (float)BB;
}

extern "C" void kernel_launch(void* const* d_in, const int* in_sizes, int n_in,
                              void* d_out, int out_size, void* d_ws, size_t ws_size,
                              hipStream_t stream) {
    const int*   cw  = (const int*)d_in[0];
    const int*   ow  = (const int*)d_in[1];
    const int*   neg = (const int*)d_in[2];
    const float* emb = (const float*)d_in[3];
    float* out     = (float*)d_out;
    float* partial = (float*)d_ws;

    if (ws_size >= TBL_OFF + TBL_BYTES) {
        uint4* tbl = (uint4*)((char*)d_ws + TBL_OFF);
        const int nq = VV * EE / 16;
        convert_fp8_kernel<<<(nq + 255) / 256, 256, 0, stream>>>(emb, tbl);
        w2v_loss_fp8_kernel<<<GRID, BLOCK, 0, stream>>>(cw, ow, neg, tbl, partial);
        w2v_reduce_kernel<<<1, 256, 0, stream>>>(partial, GRID, out);
    } else {
        w2v_loss_f32_kernel<<<BB / 16, BLOCK, 0, stream>>>(cw, ow, neg, emb, partial);
        w2v_reduce_kernel<<<1, 256, 0, stream>>>(partial, BB / 16, out);
    }
}